// Round 4
// baseline (746.760 us; speedup 1.0000x reference)
//
#include <hip/hip_runtime.h>
#include <hip/hip_bf16.h>
#include <stdint.h>
#include <math.h>

// Problem constants (fixed by the reference)
#define BATCH 2
#define S_LEN 4096
#define DMODEL 1024
#define NH 16
#define DHEAD 64
#define MTOK (BATCH * S_LEN)  // 8192

// Finite -inf sentinel: safe under -ffast-math.
#define NEG_BIG (-1.0e30f)

typedef unsigned short u16;
typedef __attribute__((ext_vector_type(8))) short bf16x8;  // 8 bf16 = 4 VGPRs
typedef __attribute__((ext_vector_type(4))) float f32x4;

__device__ __forceinline__ float b2f(u16 u) {
  union { unsigned int i; float f; } v; v.i = ((unsigned int)u) << 16; return v.f;
}
__device__ __forceinline__ u16 f2b(float f) {
  union { float f; unsigned int i; } v; v.f = f;
  unsigned int r = v.i + 0x7FFF + ((v.i >> 16) & 1);  // RNE
  return (u16)(r >> 16);
}

// ---------------------------------------------------------------------------
// Input dtype detection. Gaussian data stored as bf16: the LOW u16 of each
// u32 word is a bf16 with exponent field ~always in [100,135]. Stored as f32:
// the low u16 is mantissa bits -> exponent field uniform (~14% in range).
// flag = 1 -> buffers are bf16; flag = 0 -> buffers are f32.
// ---------------------------------------------------------------------------
__global__ void detect_dtype(const unsigned int* __restrict__ x, int* __restrict__ flag) {
  __shared__ int cnt;
  if (threadIdx.x == 0) cnt = 0;
  __syncthreads();
  int c = 0;
  for (int i = threadIdx.x; i < 4096; i += 256) {
    unsigned int w = x[i];
    int e = (w >> 7) & 0xFF;  // bf16 exponent field of the low u16
    if (e >= 100 && e <= 135) c++;
  }
  atomicAdd(&cnt, c);
  __syncthreads();
  if (threadIdx.x == 0) *flag = (cnt > 2048) ? 1 : 0;
}

// ---------------------------------------------------------------------------
// Canonicalize x -> bf16. 8192 blocks x 256 threads x 4 elems = 8,388,608.
// ---------------------------------------------------------------------------
__global__ void convert_x(const void* __restrict__ xin, u16* __restrict__ xc,
                          const int* __restrict__ flagp) {
  const int isb = *flagp;
  long e = ((long)blockIdx.x * 256 + threadIdx.x) * 4;
  if (isb) {
    *(uint2*)&xc[e] = *(const uint2*)((const u16*)xin + e);  // 8B copy
  } else {
    float4 f = *(const float4*)((const float*)xin + e);
    xc[e + 0] = f2b(f.x);
    xc[e + 1] = f2b(f.y);
    xc[e + 2] = f2b(f.z);
    xc[e + 3] = f2b(f.w);
  }
}

// ---------------------------------------------------------------------------
// Weight transpose + dtype conversion: out[n*1024+k] = bf16(W[k*1024+n])
// ---------------------------------------------------------------------------
__global__ void transpose4(const void* __restrict__ W0, const void* __restrict__ W1,
                           const void* __restrict__ W2, const void* __restrict__ W3,
                           u16* __restrict__ out, const int* __restrict__ flagp) {
  __shared__ u16 tile[32][33];
  const int isb = *flagp;
  int z = blockIdx.z;
  const void* W = (z == 0) ? W0 : (z == 1) ? W1 : (z == 2) ? W2 : W3;
  u16* o = out + (long)z * (DMODEL * DMODEL);
  int x = blockIdx.x * 32 + threadIdx.x;
  int y0 = blockIdx.y * 32;
  if (isb) {
    const u16* Wb = (const u16*)W;
#pragma unroll
    for (int i = 0; i < 32; i += 8)
      tile[threadIdx.y + i][threadIdx.x] = Wb[(long)(y0 + threadIdx.y + i) * DMODEL + x];
  } else {
    const float* Wf = (const float*)W;
#pragma unroll
    for (int i = 0; i < 32; i += 8)
      tile[threadIdx.y + i][threadIdx.x] = f2b(Wf[(long)(y0 + threadIdx.y + i) * DMODEL + x]);
  }
  __syncthreads();
  int x2 = blockIdx.y * 32 + threadIdx.x;
  int y2 = blockIdx.x * 32;
#pragma unroll
  for (int i = 0; i < 32; i += 8)
    o[(long)(y2 + threadIdx.y + i) * DMODEL + x2] = tile[threadIdx.x][threadIdx.y + i];
}

// ---------------------------------------------------------------------------
// C = A[M,K] @ Bt[N,K]^T  (128x128 tile, BK=32, plain vector-load staging)
// MODE 0: out  (dtype per flag), + bias (dtype per flag)
// MODE 1: scatter bf16 to [B,H,S,DH]   (Q and K)
// MODE 2: scatter bf16 to [B,H,DH,S]   (V transposed)
// ---------------------------------------------------------------------------
#define BM 128
#define BN 128
#define BK 32

template <int MODE>
__global__ __launch_bounds__(256)
void gemm_bt(const u16* __restrict__ A, const u16* __restrict__ Bt,
             const void* __restrict__ bias, void* __restrict__ C,
             int M, int N, int Kd, const int* __restrict__ flagp) {
  __shared__ __align__(16) u16 lA[BM * BK];
  __shared__ __align__(16) u16 lB[BN * BK];
  const int tid = threadIdx.x;
  const int w = tid >> 6;
  const int lane = tid & 63;
  const int m0 = blockIdx.y * BM;
  const int n0 = blockIdx.x * BN;
  const int wm = (w >> 1) * 64;
  const int wn = (w & 1) * 64;
  const int lc = lane & 15;
  const int lq = lane >> 4;

  f32x4 acc[4][4] = {};

  for (int k0 = 0; k0 < Kd; k0 += BK) {
    __syncthreads();  // previous tile fully consumed
#pragma unroll
    for (int v = 0; v < 2; ++v) {
      int e = (v * 256 + tid) * 8;  // element index within 128x32 tile
      int row = e >> 5, col = e & 31;
      *(bf16x8*)&lA[e] = *(const bf16x8*)(A + (long)(m0 + row) * Kd + k0 + col);
      *(bf16x8*)&lB[e] = *(const bf16x8*)(Bt + (long)(n0 + row) * Kd + k0 + col);
    }
    __syncthreads();

    bf16x8 af[4], bg[4];
#pragma unroll
    for (int i = 0; i < 4; ++i)
      af[i] = *(const bf16x8*)&lA[(wm + i * 16 + lc) * BK + lq * 8];
#pragma unroll
    for (int j = 0; j < 4; ++j)
      bg[j] = *(const bf16x8*)&lB[(wn + j * 16 + lc) * BK + lq * 8];
#pragma unroll
    for (int i = 0; i < 4; ++i)
#pragma unroll
      for (int j = 0; j < 4; ++j)
        acc[i][j] = __builtin_amdgcn_mfma_f32_16x16x32_bf16(af[i], bg[j], acc[i][j], 0, 0, 0);
  }

  // Epilogue: C/D layout col=lane&15, row=(lane>>4)*4+reg
  int isb = 1;
  if (MODE == 0) isb = *flagp;
#pragma unroll
  for (int i = 0; i < 4; ++i) {
#pragma unroll
    for (int j = 0; j < 4; ++j) {
      int n = n0 + wn + j * 16 + lc;
      float bv = 0.0f;
      if (MODE == 0) {
        if (isb) bv = b2f(((const u16*)bias)[n]);
        else     bv = ((const float*)bias)[n];
      }
#pragma unroll
      for (int r = 0; r < 4; ++r) {
        int m = m0 + wm + i * 16 + lq * 4 + r;
        float v = acc[i][j][r] + bv;
        if (MODE == 0) {
          if (isb) ((u16*)C)[(long)m * N + n] = f2b(v);
          else     ((float*)C)[(long)m * N + n] = v;
        } else {
          int b = m >> 12, s = m & (S_LEN - 1);
          int h = n >> 6, dh = n & (DHEAD - 1);
          if (MODE == 1)
            ((u16*)C)[(((long)(b * NH + h)) * S_LEN + s) * DHEAD + dh] = f2b(v);
          else
            ((u16*)C)[(((long)(b * NH + h)) * DHEAD + dh) * S_LEN + s] = f2b(v);
        }
      }
    }
  }
}

// ---------------------------------------------------------------------------
// Flash attention (causal). Q,K: [B,H,S,DH]; Vt: [B,H,DH,S]; ctx: [B,S,H*DH]
// 1 block = (b, h, 64 q-rows). 4 waves, each owns 16 q-rows.
// ---------------------------------------------------------------------------
__global__ __launch_bounds__(256)
void flash_attn(const u16* __restrict__ Q, const u16* __restrict__ K,
                const u16* __restrict__ Vt, u16* __restrict__ ctx) {
  __shared__ __align__(16) u16 lQ[64 * 64];
  __shared__ __align__(16) u16 lK[64 * 64];
  __shared__ __align__(16) u16 lV[64 * 64];  // [dh][kv]
  __shared__ __align__(16) u16 lP[4][16 * 64];

  const int tid = threadIdx.x;
  const int w = tid >> 6;
  const int lane = tid & 63;
  const int q0 = blockIdx.x * 64;
  const int h = blockIdx.y;
  const int b = blockIdx.z;
  const int bh = b * NH + h;
  const u16* Qb = Q + (long)bh * S_LEN * DHEAD;
  const u16* Kb = K + (long)bh * S_LEN * DHEAD;
  const u16* Vb = Vt + (long)bh * DHEAD * S_LEN;
  const int lc = lane & 15;
  const int lq = lane >> 4;

  // stage Q tile once (contiguous 64x64 slab)
#pragma unroll
  for (int v = 0; v < 2; ++v) {
    int e = (v * 256 + tid) * 8;
    *(bf16x8*)&lQ[e] = *(const bf16x8*)(Qb + q0 * DHEAD + e);
  }

  float m_s[4], l_s[4];
  f32x4 o_acc[4] = {};
#pragma unroll
  for (int r = 0; r < 4; ++r) { m_s[r] = NEG_BIG; l_s[r] = 0.0f; }

  for (int k0 = 0; k0 <= q0; k0 += 64) {
    __syncthreads();  // previous tile consumed (and Q stores visible, 1st iter)
#pragma unroll
    for (int v = 0; v < 2; ++v) {
      int e = (v * 256 + tid) * 8;
      *(bf16x8*)&lK[e] = *(const bf16x8*)(Kb + k0 * DHEAD + e);
      int dh = e >> 6, kv = e & 63;
      *(bf16x8*)&lV[e] = *(const bf16x8*)(Vb + (long)dh * S_LEN + k0 + kv);
    }
    __syncthreads();

    // S = Q K^T (per wave: 16 q-rows x 64 kv)
    bf16x8 aq[2];
#pragma unroll
    for (int t = 0; t < 2; ++t)
      aq[t] = *(const bf16x8*)&lQ[(w * 16 + lc) * 64 + t * 32 + lq * 8];
    f32x4 sc[4] = {};
#pragma unroll
    for (int j = 0; j < 4; ++j)
#pragma unroll
      for (int t = 0; t < 2; ++t) {
        bf16x8 bk = *(const bf16x8*)&lK[(j * 16 + lc) * 64 + t * 32 + lq * 8];
        sc[j] = __builtin_amdgcn_mfma_f32_16x16x32_bf16(aq[t], bk, sc[j], 0, 0, 0);
      }

    // scale + causal mask + online softmax (all-finite arithmetic)
    float p[4][4], rmax[4];
#pragma unroll
    for (int r = 0; r < 4; ++r) rmax[r] = NEG_BIG;
    const int qrow_base = q0 + w * 16 + lq * 4;
#pragma unroll
    for (int j = 0; j < 4; ++j) {
      int kv = k0 + j * 16 + lc;
#pragma unroll
      for (int r = 0; r < 4; ++r) {
        float v = sc[j][r] * 0.125f;  // 1/sqrt(64)
        if (k0 == q0 && kv > qrow_base + r) v = NEG_BIG;
        p[j][r] = v;
        rmax[r] = fmaxf(rmax[r], v);
      }
    }
#pragma unroll
    for (int off = 1; off < 16; off <<= 1)
#pragma unroll
      for (int r = 0; r < 4; ++r)
        rmax[r] = fmaxf(rmax[r], __shfl_xor(rmax[r], off, 64));
    float alpha[4], rsum[4];
#pragma unroll
    for (int r = 0; r < 4; ++r) {
      float mn = fmaxf(m_s[r], rmax[r]);
      alpha[r] = __expf(m_s[r] - mn);   // exp(-1e30) == 0 on first tile
      m_s[r] = mn;
      rsum[r] = 0.0f;
    }
#pragma unroll
    for (int j = 0; j < 4; ++j)
#pragma unroll
      for (int r = 0; r < 4; ++r) {
        float e = __expf(p[j][r] - m_s[r]);  // masked: exp(~-1e30) == 0
        p[j][r] = e;
        rsum[r] += e;
      }
#pragma unroll
    for (int off = 1; off < 16; off <<= 1)
#pragma unroll
      for (int r = 0; r < 4; ++r)
        rsum[r] += __shfl_xor(rsum[r], off, 64);
#pragma unroll
    for (int r = 0; r < 4; ++r) l_s[r] = l_s[r] * alpha[r] + rsum[r];
#pragma unroll
    for (int jd = 0; jd < 4; ++jd)
#pragma unroll
      for (int r = 0; r < 4; ++r) o_acc[jd][r] *= alpha[r];

    // P: C-layout regs -> LDS -> A-layout frags
#pragma unroll
    for (int j = 0; j < 4; ++j)
#pragma unroll
      for (int r = 0; r < 4; ++r)
        lP[w][(lq * 4 + r) * 64 + j * 16 + lc] = f2b(p[j][r]);
    __syncthreads();

    // O += P @ V  (B-operand from Vt: contiguous kv per dh row)
#pragma unroll
    for (int t = 0; t < 2; ++t) {
      bf16x8 ap = *(const bf16x8*)&lP[w][lc * 64 + t * 32 + lq * 8];
#pragma unroll
      for (int jd = 0; jd < 4; ++jd) {
        bf16x8 bv = *(const bf16x8*)&lV[(jd * 16 + lc) * 64 + t * 32 + lq * 8];
        o_acc[jd] = __builtin_amdgcn_mfma_f32_16x16x32_bf16(ap, bv, o_acc[jd], 0, 0, 0);
      }
    }
  }

  // epilogue: ctx[b, q, h*64+dh]
#pragma unroll
  for (int r = 0; r < 4; ++r) {
    float inv = 1.0f / l_s[r];
    int q = q0 + w * 16 + lq * 4 + r;
#pragma unroll
    for (int jd = 0; jd < 4; ++jd)
      ctx[((long)(b * S_LEN + q)) * DMODEL + h * DHEAD + jd * 16 + lc] =
          f2b(o_acc[jd][r] * inv);
  }
}

// ---------------------------------------------------------------------------
// ws layout (u16 elems): wt[4M] | Q[8M] | Vt[8M] | xc-then-ctx[8M] | flag
//   = 56 MB + 4 B.   K rides in d_out until the final GEMM overwrites it.
// ---------------------------------------------------------------------------
extern "C" void kernel_launch(void* const* d_in, const int* in_sizes, int n_in,
                              void* d_out, int out_size, void* d_ws, size_t ws_size,
                              hipStream_t stream) {
  const void* x  = d_in[0];
  const void* Wq = d_in[1];
  const void* Wk = d_in[2];
  const void* Wv = d_in[3];
  const void* Wo = d_in[4];
  const void* bo = d_in[5];
  u16* ws = (u16*)d_ws;

  u16* wt  = ws;                        // 4 * 1,048,576
  u16* wtq = wt;
  u16* wtk = wt + 1048576;
  u16* wtv = wt + 2097152;
  u16* wto = wt + 3145728;
  u16* Qb  = ws + 4194304;              // 8,388,608
  u16* Vtb = ws + 12582912;             // 8,388,608
  u16* xc  = ws + 20971520;             // 8,388,608 (reused as ctx after QKV)
  u16* ctx = xc;
  int* flag = (int*)(ws + 29360128);
  u16* Kb  = (u16*)d_out;               // bf16 K scratch in d_out (16 MB)

  detect_dtype<<<1, 256, 0, stream>>>((const unsigned int*)x, flag);
  convert_x<<<8192, 256, 0, stream>>>(x, xc, flag);
  transpose4<<<dim3(32, 32, 4), dim3(32, 8), 0, stream>>>(Wq, Wk, Wv, Wo, wt, flag);

  dim3 g(DMODEL / BN, MTOK / BM), blk(256);
  gemm_bt<1><<<g, blk, 0, stream>>>(xc, wtq, nullptr, Qb,  MTOK, DMODEL, DMODEL, flag);
  gemm_bt<1><<<g, blk, 0, stream>>>(xc, wtk, nullptr, Kb,  MTOK, DMODEL, DMODEL, flag);
  gemm_bt<2><<<g, blk, 0, stream>>>(xc, wtv, nullptr, Vtb, MTOK, DMODEL, DMODEL, flag);

  flash_attn<<<dim3(S_LEN / 64, NH, BATCH), 256, 0, stream>>>(Qb, Kb, Vtb, ctx);

  gemm_bt<0><<<g, blk, 0, stream>>>(ctx, wto, bo, d_out, MTOK, DMODEL, DMODEL, flag);
}

// Round 5
// 547.733 us; speedup vs baseline: 1.3634x; 1.3634x over previous
//
#include <hip/hip_runtime.h>
#include <hip/hip_bf16.h>
#include <stdint.h>
#include <math.h>

// Problem constants (fixed by the reference)
#define BATCH 2
#define S_LEN 4096
#define DMODEL 1024
#define NH 16
#define DHEAD 64
#define MTOK (BATCH * S_LEN)  // 8192

// Finite -inf sentinel: safe under -ffast-math.
#define NEG_BIG (-1.0e30f)

typedef unsigned short u16;
typedef __attribute__((ext_vector_type(8))) short bf16x8;  // 8 bf16 = 4 VGPRs
typedef __attribute__((ext_vector_type(4))) float f32x4;
typedef __attribute__((ext_vector_type(4))) unsigned short u16x4;

__device__ __forceinline__ float b2f(u16 u) {
  union { unsigned int i; float f; } v; v.i = ((unsigned int)u) << 16; return v.f;
}
__device__ __forceinline__ u16 f2b(float f) {
  union { float f; unsigned int i; } v; v.f = f;
  unsigned int r = v.i + 0x7FFF + ((v.i >> 16) & 1);  // RNE
  return (u16)(r >> 16);
}

// ---------------------------------------------------------------------------
// Input dtype detection (bf16 vs f32 buffers) — statistical, see round 4.
// flag = 1 -> bf16; flag = 0 -> f32.
// ---------------------------------------------------------------------------
__global__ void detect_dtype(const unsigned int* __restrict__ x, int* __restrict__ flag) {
  __shared__ int cnt;
  if (threadIdx.x == 0) cnt = 0;
  __syncthreads();
  int c = 0;
  for (int i = threadIdx.x; i < 4096; i += 256) {
    unsigned int w = x[i];
    int e = (w >> 7) & 0xFF;  // bf16 exponent field of the low u16
    if (e >= 100 && e <= 135) c++;
  }
  atomicAdd(&cnt, c);
  __syncthreads();
  if (threadIdx.x == 0) *flag = (cnt > 2048) ? 1 : 0;
}

// ---------------------------------------------------------------------------
// Canonicalize x -> bf16. 8192 blocks x 256 threads x 4 elems = 8,388,608.
// ---------------------------------------------------------------------------
__global__ void convert_x(const void* __restrict__ xin, u16* __restrict__ xc,
                          const int* __restrict__ flagp) {
  const int isb = *flagp;
  long e = ((long)blockIdx.x * 256 + threadIdx.x) * 4;
  if (isb) {
    *(uint2*)&xc[e] = *(const uint2*)((const u16*)xin + e);  // 8B copy
  } else {
    float4 f = *(const float4*)((const float*)xin + e);
    xc[e + 0] = f2b(f.x);
    xc[e + 1] = f2b(f.y);
    xc[e + 2] = f2b(f.z);
    xc[e + 3] = f2b(f.w);
  }
}

// ---------------------------------------------------------------------------
// Weight transpose + dtype conversion: out[n*1024+k] = bf16(W[k*1024+n])
// ---------------------------------------------------------------------------
__global__ void transpose4(const void* __restrict__ W0, const void* __restrict__ W1,
                           const void* __restrict__ W2, const void* __restrict__ W3,
                           u16* __restrict__ out, const int* __restrict__ flagp) {
  __shared__ u16 tile[32][33];
  const int isb = *flagp;
  int z = blockIdx.z;
  const void* W = (z == 0) ? W0 : (z == 1) ? W1 : (z == 2) ? W2 : W3;
  u16* o = out + (long)z * (DMODEL * DMODEL);
  int x = blockIdx.x * 32 + threadIdx.x;
  int y0 = blockIdx.y * 32;
  if (isb) {
    const u16* Wb = (const u16*)W;
#pragma unroll
    for (int i = 0; i < 32; i += 8)
      tile[threadIdx.y + i][threadIdx.x] = Wb[(long)(y0 + threadIdx.y + i) * DMODEL + x];
  } else {
    const float* Wf = (const float*)W;
#pragma unroll
    for (int i = 0; i < 32; i += 8)
      tile[threadIdx.y + i][threadIdx.x] = f2b(Wf[(long)(y0 + threadIdx.y + i) * DMODEL + x]);
  }
  __syncthreads();
  int x2 = blockIdx.y * 32 + threadIdx.x;
  int y2 = blockIdx.x * 32;
#pragma unroll
  for (int i = 0; i < 32; i += 8)
    o[(long)(y2 + threadIdx.y + i) * DMODEL + x2] = tile[threadIdx.x][threadIdx.y + i];
}

// ---------------------------------------------------------------------------
// C = A[M,K] @ Bt[N,K]^T  (128x128 tile, BK=32, plain vector-load staging)
// MODE 0: out  (dtype per flag), + bias (dtype per flag)
// MODE 1: scatter bf16 to [B,H,S,DH]   (Q and K)
// MODE 2: scatter bf16 to [B,H,DH,S]   (V transposed)
// ---------------------------------------------------------------------------
#define BM 128
#define BN 128
#define BK 32

template <int MODE>
__global__ __launch_bounds__(256)
void gemm_bt(const u16* __restrict__ A, const u16* __restrict__ Bt,
             const void* __restrict__ bias, void* __restrict__ C,
             int M, int N, int Kd, const int* __restrict__ flagp) {
  __shared__ __align__(16) u16 lA[BM * BK];
  __shared__ __align__(16) u16 lB[BN * BK];
  const int tid = threadIdx.x;
  const int w = tid >> 6;
  const int lane = tid & 63;
  const int m0 = blockIdx.y * BM;
  const int n0 = blockIdx.x * BN;
  const int wm = (w >> 1) * 64;
  const int wn = (w & 1) * 64;
  const int lc = lane & 15;
  const int lq = lane >> 4;

  f32x4 acc[4][4] = {};

  for (int k0 = 0; k0 < Kd; k0 += BK) {
    __syncthreads();  // previous tile fully consumed
#pragma unroll
    for (int v = 0; v < 2; ++v) {
      int e = (v * 256 + tid) * 8;  // element index within 128x32 tile
      int row = e >> 5, col = e & 31;
      *(bf16x8*)&lA[e] = *(const bf16x8*)(A + (long)(m0 + row) * Kd + k0 + col);
      *(bf16x8*)&lB[e] = *(const bf16x8*)(Bt + (long)(n0 + row) * Kd + k0 + col);
    }
    __syncthreads();

    bf16x8 af[4], bg[4];
#pragma unroll
    for (int i = 0; i < 4; ++i)
      af[i] = *(const bf16x8*)&lA[(wm + i * 16 + lc) * BK + lq * 8];
#pragma unroll
    for (int j = 0; j < 4; ++j)
      bg[j] = *(const bf16x8*)&lB[(wn + j * 16 + lc) * BK + lq * 8];
#pragma unroll
    for (int i = 0; i < 4; ++i)
#pragma unroll
      for (int j = 0; j < 4; ++j)
        acc[i][j] = __builtin_amdgcn_mfma_f32_16x16x32_bf16(af[i], bg[j], acc[i][j], 0, 0, 0);
  }

  // Epilogue: C/D layout col=lane&15, row=(lane>>4)*4+reg
  int isb = 1;
  if (MODE == 0) isb = *flagp;
#pragma unroll
  for (int i = 0; i < 4; ++i) {
#pragma unroll
    for (int j = 0; j < 4; ++j) {
      int n = n0 + wn + j * 16 + lc;
      float bv = 0.0f;
      if (MODE == 0) {
        if (isb) bv = b2f(((const u16*)bias)[n]);
        else     bv = ((const float*)bias)[n];
      }
#pragma unroll
      for (int r = 0; r < 4; ++r) {
        int m = m0 + wm + i * 16 + lq * 4 + r;
        float v = acc[i][j][r] + bv;
        if (MODE == 0) {
          if (isb) ((u16*)C)[(long)m * N + n] = f2b(v);
          else     ((float*)C)[(long)m * N + n] = v;
        } else {
          int b = m >> 12, s = m & (S_LEN - 1);
          int h = n >> 6, dh = n & (DHEAD - 1);
          if (MODE == 1)
            ((u16*)C)[(((long)(b * NH + h)) * S_LEN + s) * DHEAD + dh] = f2b(v);
          else
            ((u16*)C)[(((long)(b * NH + h)) * DHEAD + dh) * S_LEN + s] = f2b(v);
        }
      }
    }
  }
}

// ---------------------------------------------------------------------------
// Flash attention v2 (causal), S^T formulation.
//   Q,K: [B,H,S,DH]; Vt: [B,H,DH,S]; ctx: [B,S,H*DH]
// 1 block = (b, h, 64 q-rows); 4 waves, each owns 16 q-COLUMNS (q = lane&15).
// S^T = K·Q^T  -> C-layout col = q  => softmax stats are lane-local scalars.
// O^T = V^T·P^T -> col = q again    => rescale is lane-local; all LDS frag
// reads are ds_read_b128 on rows padded to 72 u16 (144 B) = no bank conflicts.
// ---------------------------------------------------------------------------
#define LDP 72  // padded row stride in u16 (144 B = 36 banks -> 2 lanes/bank)

__global__ __launch_bounds__(256)
void flash_attn(const u16* __restrict__ Q, const u16* __restrict__ K,
                const u16* __restrict__ Vt, u16* __restrict__ ctx) {
  __shared__ __align__(16) u16 lK[64 * LDP];       // [kv][dh]
  __shared__ __align__(16) u16 lV[64 * LDP];       // [dh][kv]
  __shared__ __align__(16) u16 lP[4][16 * LDP];    // per-wave P[q][kv]

  const int tid = threadIdx.x;
  const int w = tid >> 6;
  const int lane = tid & 63;
  const int lc = lane & 15;
  const int lq = lane >> 4;
  // reversed grid.x: longest (most k-tiles) blocks dispatch first
  const int q0 = (gridDim.x - 1 - blockIdx.x) * 64;
  const int h = blockIdx.y;
  const int b = blockIdx.z;
  const int bh = b * NH + h;
  const u16* Qb = Q + (long)bh * S_LEN * DHEAD;
  const u16* Kb = K + (long)bh * S_LEN * DHEAD;
  const u16* Vb = Vt + (long)bh * DHEAD * S_LEN;

  const int myq = q0 + w * 16 + lc;  // this lane's q column

  // Q B-operand frags direct from global (loop-invariant): Q[q=myq][k=t*32+lq*8..+7]
  bf16x8 aq[2];
#pragma unroll
  for (int t = 0; t < 2; ++t)
    aq[t] = *(const bf16x8*)(Qb + (long)myq * DHEAD + t * 32 + lq * 8);

  float m_s = NEG_BIG, l_s = 0.0f;
  f32x4 o_acc[4] = {};

  for (int k0 = 0; k0 <= q0; k0 += 64) {
    __syncthreads();  // previous tile's frag reads complete
#pragma unroll
    for (int v = 0; v < 2; ++v) {
      int e = (v * 256 + tid) * 8;
      int row = e >> 6, col = e & 63;
      *(bf16x8*)&lK[row * LDP + col] = *(const bf16x8*)(Kb + (long)(k0 + row) * DHEAD + col);
      *(bf16x8*)&lV[row * LDP + col] = *(const bf16x8*)(Vb + (long)row * S_LEN + k0 + col);
    }
    __syncthreads();

    // S^T tile: kv (4x16 rows) x q (16 cols): sc[jm] = K-rows . Q^T
    f32x4 sc[4] = {};
#pragma unroll
    for (int jm = 0; jm < 4; ++jm)
#pragma unroll
      for (int t = 0; t < 2; ++t) {
        bf16x8 ak = *(const bf16x8*)&lK[(jm * 16 + lc) * LDP + t * 32 + lq * 8];
        sc[jm] = __builtin_amdgcn_mfma_f32_16x16x32_bf16(ak, aq[t], sc[jm], 0, 0, 0);
      }

    // scale + causal mask; element (kv = k0+jm*16+lq*4+r, q = myq)
    const bool diag = (k0 == q0);
    float vv[4][4];
    float tmax = NEG_BIG;
#pragma unroll
    for (int jm = 0; jm < 4; ++jm)
#pragma unroll
      for (int r = 0; r < 4; ++r) {
        float v = sc[jm][r] * 0.125f;  // 1/sqrt(64)
        if (diag && (k0 + jm * 16 + lq * 4 + r > myq)) v = NEG_BIG;
        vv[jm][r] = v;
        tmax = fmaxf(tmax, v);
      }
    // cross-quad reduction (lanes lc, lc+16, lc+32, lc+48 share q=lc)
    tmax = fmaxf(tmax, __shfl_xor(tmax, 16, 64));
    tmax = fmaxf(tmax, __shfl_xor(tmax, 32, 64));
    float mnew = fmaxf(m_s, tmax);
    float alpha = __expf(m_s - mnew);
    float lsum = 0.0f;
    u16x4 pb[4];
#pragma unroll
    for (int jm = 0; jm < 4; ++jm)
#pragma unroll
      for (int r = 0; r < 4; ++r) {
        float e = __expf(vv[jm][r] - mnew);
        lsum += e;
        pb[jm][r] = f2b(e);
      }
    lsum += __shfl_xor(lsum, 16, 64);
    lsum += __shfl_xor(lsum, 32, 64);
    m_s = mnew;
    l_s = l_s * alpha + lsum;
#pragma unroll
    for (int jd = 0; jd < 4; ++jd)
#pragma unroll
      for (int r = 0; r < 4; ++r) o_acc[jd][r] *= alpha;

    // P[q][kv] to wave-private LDS: 4x ds_write_b64 (r=0..3 contiguous in kv)
#pragma unroll
    for (int jm = 0; jm < 4; ++jm)
      *(u16x4*)&lP[w][lc * LDP + jm * 16 + lq * 4] = pb[jm];
    // wave-private region: no barrier needed (lgkmcnt ordering only)

    // O^T += V^T . P^T : o_acc[jd] rows dh=jd*16+lq*4+r, col q=lc
#pragma unroll
    for (int t = 0; t < 2; ++t) {
      bf16x8 bp = *(const bf16x8*)&lP[w][lc * LDP + t * 32 + lq * 8];
#pragma unroll
      for (int jd = 0; jd < 4; ++jd) {
        bf16x8 av = *(const bf16x8*)&lV[(jd * 16 + lc) * LDP + t * 32 + lq * 8];
        o_acc[jd] = __builtin_amdgcn_mfma_f32_16x16x32_bf16(av, bp, o_acc[jd], 0, 0, 0);
      }
    }
  }

  // epilogue: ctx[b, q=myq, h*64 + dh], dh = jd*16 + lq*4 + r  (8B stores)
  float inv = 1.0f / l_s;
  u16* cp = ctx + ((long)(b * S_LEN + myq)) * DMODEL + h * DHEAD;
#pragma unroll
  for (int jd = 0; jd < 4; ++jd) {
    u16x4 ov;
#pragma unroll
    for (int r = 0; r < 4; ++r) ov[r] = f2b(o_acc[jd][r] * inv);
    *(u16x4*)&cp[jd * 16 + lq * 4] = ov;
  }
}

// ---------------------------------------------------------------------------
// ws layout (u16 elems): wt[4M] | Q[8M] | Vt[8M] | xc-then-ctx[8M] | flag
//   = 56 MB + 4 B.   K rides in d_out until the final GEMM overwrites it.
// ---------------------------------------------------------------------------
extern "C" void kernel_launch(void* const* d_in, const int* in_sizes, int n_in,
                              void* d_out, int out_size, void* d_ws, size_t ws_size,
                              hipStream_t stream) {
  const void* x  = d_in[0];
  const void* Wq = d_in[1];
  const void* Wk = d_in[2];
  const void* Wv = d_in[3];
  const void* Wo = d_in[4];
  const void* bo = d_in[5];
  u16* ws = (u16*)d_ws;

  u16* wt  = ws;                        // 4 * 1,048,576
  u16* wtq = wt;
  u16* wtk = wt + 1048576;
  u16* wtv = wt + 2097152;
  u16* wto = wt + 3145728;
  u16* Qb  = ws + 4194304;              // 8,388,608
  u16* Vtb = ws + 12582912;             // 8,388,608
  u16* xc  = ws + 20971520;             // 8,388,608 (reused as ctx after QKV)
  u16* ctx = xc;
  int* flag = (int*)(ws + 29360128);
  u16* Kb  = (u16*)d_out;               // bf16 K scratch in d_out (16 MB)

  detect_dtype<<<1, 256, 0, stream>>>((const unsigned int*)x, flag);
  convert_x<<<8192, 256, 0, stream>>>(x, xc, flag);
  transpose4<<<dim3(32, 32, 4), dim3(32, 8), 0, stream>>>(Wq, Wk, Wv, Wo, wt, flag);

  dim3 g(DMODEL / BN, MTOK / BM), blk(256);
  gemm_bt<1><<<g, blk, 0, stream>>>(xc, wtq, nullptr, Qb,  MTOK, DMODEL, DMODEL, flag);
  gemm_bt<1><<<g, blk, 0, stream>>>(xc, wtk, nullptr, Kb,  MTOK, DMODEL, DMODEL, flag);
  gemm_bt<2><<<g, blk, 0, stream>>>(xc, wtv, nullptr, Vtb, MTOK, DMODEL, DMODEL, flag);

  flash_attn<<<dim3(S_LEN / 64, NH, BATCH), 256, 0, stream>>>(Qb, Kb, Vtb, ctx);

  gemm_bt<0><<<g, blk, 0, stream>>>(ctx, wto, bo, d_out, MTOK, DMODEL, DMODEL, flag);
}